// Round 1
// baseline (674.289 us; speedup 1.0000x reference)
//
#include <hip/hip_runtime.h>

#define N    1024
#define BSZ  32
#define PS   480     // per-sample param stride: 169 W13 + 147 w1 + 147 w2 + 9 kA
#define HID  100

// ---------------------------------------------------------------------------
// Kernel 1: per-sample MLPs + composed 13x13 kernel
// ---------------------------------------------------------------------------
__global__ __launch_bounds__(256) void prep_kernel(
    const float* __restrict__ kernelA,
    const float* __restrict__ fc1_w1, const float* __restrict__ fc1_b1,
    const float* __restrict__ fc1_w2, const float* __restrict__ fc1_b2,
    const float* __restrict__ fc2_w1, const float* __restrict__ fc2_b1,
    const float* __restrict__ fc2_w2, const float* __restrict__ fc2_b2,
    float* __restrict__ params)
{
    int b = blockIdx.x, t = threadIdx.x;
    __shared__ float w[9], h1[HID], h2[HID], w1[147], w2[147];
    if (t < 9) w[t] = kernelA[b * 9 + t];
    __syncthreads();
    if (t < HID) {
        float s1 = fc1_b1[t], s2 = fc2_b1[t];
        #pragma unroll
        for (int i = 0; i < 9; ++i) {
            s1 = fmaf(w[i], fc1_w1[i * HID + t], s1);
            s2 = fmaf(w[i], fc2_w1[i * HID + t], s2);
        }
        h1[t] = fmaxf(s1, 0.f);
        h2[t] = fmaxf(s2, 0.f);
    }
    __syncthreads();
    if (t < 147) {
        float s1 = fc1_b2[t], s2 = fc2_b2[t];
        for (int i = 0; i < HID; ++i) {
            s1 = fmaf(h1[i], fc1_w2[i * 147 + t], s1);
            s2 = fmaf(h2[i], fc2_w2[i * 147 + t], s2);
        }
        w1[t] = s1;
        w2[t] = s2;
    }
    __syncthreads();
    float* P = params + b * PS;
    if (t < 169) {   // W13[ey][ex] = sum_m sum_{d1+d2=e} w1[m,d1] * w2[m,d2]
        int ey = t / 13, ex = t % 13;
        float s = 0.f;
        for (int m = 0; m < 3; ++m)
            for (int d1y = 0; d1y < 7; ++d1y) {
                int d2y = ey - d1y;
                if (d2y < 0 || d2y > 6) continue;
                for (int d1x = 0; d1x < 7; ++d1x) {
                    int d2x = ex - d1x;
                    if (d2x < 0 || d2x > 6) continue;
                    s = fmaf(w1[m * 49 + d1y * 7 + d1x],
                             w2[m * 49 + d2y * 7 + d2x], s);
                }
            }
        P[t] = s;
    }
    if (t < 147) { P[169 + t] = w1[t]; P[316 + t] = w2[t]; }
    if (t < 9)   P[463 + t] = w[t];
}

// ---------------------------------------------------------------------------
// Kernel 2: interior — composed 13x13 conv over r (exact for px >=3 from edge)
// Tile 32 rows x 128 cols, 256 threads, each thread computes 2x8 outputs.
// ---------------------------------------------------------------------------
#define TR 32
#define TC 128
#define XR 46      // x tile rows  (TR + 14)
#define XC 142     // x tile cols  (TC + 14)
#define RRW 44     // r tile rows  (TR + 12)
#define RC 140     // r tile cols  (TC + 12)

__global__ __launch_bounds__(256, 3) void main_kernel(
    const float* __restrict__ X, const float* __restrict__ F,
    const float* __restrict__ params, float* __restrict__ out)
{
    __shared__ float xs[XR * XC];
    __shared__ float rs[RRW * RC];
    const int t  = threadIdx.x;
    const int b  = blockIdx.z;
    const int y0 = blockIdx.y * TR;
    const int x0 = blockIdx.x * TC;
    const float* P  = params + b * PS;
    const float* Xb = X + (size_t)b * N * N;
    const float* Fb = F + (size_t)b * N * N;
    float*       Ob = out + (size_t)b * N * N;

    // stage x tile (halo 7): rows y0-7 .. y0+38, cols x0-7 .. x0+134
    for (int idx = t; idx < XR * XC; idx += 256) {
        int i = idx / XC, j = idx % XC;
        int gy = y0 - 7 + i, gx = x0 - 7 + j;
        xs[idx] = (gy >= 0 && gy < N && gx >= 0 && gx < N) ? Xb[gy * N + gx] : 0.f;
    }
    __syncthreads();

    float ka[9];
    #pragma unroll
    for (int i = 0; i < 9; ++i) ka[i] = P[463 + i];  // uniform -> SGPR

    // r = f - corr3x3(x, kA), zero outside image
    for (int idx = t; idx < RRW * RC; idx += 256) {
        int i = idx / RC, j = idx % RC;
        int gy = y0 - 6 + i, gx = x0 - 6 + j;
        float v = 0.f;
        if (gy >= 0 && gy < N && gx >= 0 && gx < N) {
            float s = 0.f;
            #pragma unroll
            for (int dy = 0; dy < 3; ++dy)
                #pragma unroll
                for (int dx = 0; dx < 3; ++dx)
                    s = fmaf(ka[dy * 3 + dx], xs[(i + dy) * XC + (j + dx)], s);
            v = Fb[gy * N + gx] - s;
        }
        rs[idx] = v;
    }
    __syncthreads();

    const int tx8 = (t & 15) * 8;   // output col block within tile
    const int ty2 = (t >> 4) * 2;   // output row pair within tile

    float acc0[8] = {0.f, 0.f, 0.f, 0.f, 0.f, 0.f, 0.f, 0.f};
    float acc1[8] = {0.f, 0.f, 0.f, 0.f, 0.f, 0.f, 0.f, 0.f};

    // r-row rr serves output row 0 with tap row rr and row 1 with tap row rr-1
    for (int rr = 0; rr < 14; ++rr) {
        float win[20];
        const float* rp = &rs[(ty2 + rr) * RC + tx8];
        #pragma unroll
        for (int q = 0; q < 5; ++q) {
            float4 v = *reinterpret_cast<const float4*>(rp + 4 * q);
            win[4 * q + 0] = v.x; win[4 * q + 1] = v.y;
            win[4 * q + 2] = v.z; win[4 * q + 3] = v.w;
        }
        if (rr < 13) {
            #pragma unroll
            for (int c = 0; c < 13; ++c) {
                float tv = P[rr * 13 + c];   // block-uniform -> s_load
                #pragma unroll
                for (int j = 0; j < 8; ++j)
                    acc0[j] = fmaf(win[c + j], tv, acc0[j]);
            }
        }
        if (rr >= 1) {
            #pragma unroll
            for (int c = 0; c < 13; ++c) {
                float tv = P[(rr - 1) * 13 + c];
                #pragma unroll
                for (int j = 0; j < 8; ++j)
                    acc1[j] = fmaf(win[c + j], tv, acc1[j]);
            }
        }
    }

    // epilogue: out = x + G2 (full tiles, all in range)
    {
        int gy = y0 + ty2, gx = x0 + tx8;
        const float* xp0 = &xs[(ty2 + 7) * XC + (tx8 + 7)];
        const float* xp1 = xp0 + XC;
        float4 o;
        o.x = xp0[0] + acc0[0]; o.y = xp0[1] + acc0[1];
        o.z = xp0[2] + acc0[2]; o.w = xp0[3] + acc0[3];
        *reinterpret_cast<float4*>(&Ob[gy * N + gx]) = o;
        o.x = xp0[4] + acc0[4]; o.y = xp0[5] + acc0[5];
        o.z = xp0[6] + acc0[6]; o.w = xp0[7] + acc0[7];
        *reinterpret_cast<float4*>(&Ob[gy * N + gx + 4]) = o;
        o.x = xp1[0] + acc1[0]; o.y = xp1[1] + acc1[1];
        o.z = xp1[2] + acc1[2]; o.w = xp1[3] + acc1[3];
        *reinterpret_cast<float4*>(&Ob[(gy + 1) * N + gx]) = o;
        o.x = xp1[4] + acc1[4]; o.y = xp1[5] + acc1[5];
        o.z = xp1[6] + acc1[6]; o.w = xp1[7] + acc1[7];
        *reinterpret_cast<float4*>(&Ob[(gy + 1) * N + gx + 4]) = o;
    }
}

// ---------------------------------------------------------------------------
// Kernel 3: exact two-stage recompute of the width-3 border band (overwrites).
// Unified over 4 edges: "across" = perpendicular-to-edge coord, "along" = edge.
// tmp band: 6 across-positions x (128+6) along, 3 channels, in LDS.
// ---------------------------------------------------------------------------
#define AXX 14     // x across size
#define AXU 142    // x along size
#define ARR 12     // r across size
#define ARU 140    // r along size
#define ATA 6      // tmp across size
#define ATU 134    // tmp along size

__global__ __launch_bounds__(256) void border_kernel(
    const float* __restrict__ X, const float* __restrict__ F,
    const float* __restrict__ params, float* __restrict__ out)
{
    __shared__ float xs[AXX * AXU];
    __shared__ float rs[ARR * ARU];
    __shared__ float tmp[3 * ATA * ATU];
    __shared__ float sw1[147], sw2[147];

    const int  t    = threadIdx.x;
    const int  b    = blockIdx.y;
    const int  seg  = blockIdx.x;
    const int  edge = seg >> 3;          // 0 top, 1 bottom, 2 left, 3 right
    const int  s    = seg & 7;
    const bool vert = edge >= 2;
    const bool hi   = (edge == 1) || (edge == 3);
    const int  T0   = hi ? (N - 6) : 0;  // tmp across origin
    const int  V0   = hi ? (N - 3) : 0;  // output across origin
    const int  D    = hi ? 3 : 0;        // V0 - T0
    const int  u0   = vert ? (3 + s * 128) : (s * 128);
    const int  acr0x = T0 - 4, al0x = u0 - 7;
    const int  acr0r = T0 - 3, al0r = u0 - 6;

    const float* P  = params + b * PS;
    const float* Xb = X + (size_t)b * N * N;
    const float* Fb = F + (size_t)b * N * N;
    float*       Ob = out + (size_t)b * N * N;

    if (t < 147) { sw1[t] = P[169 + t]; sw2[t] = P[316 + t]; }
    float ka[9];
    #pragma unroll
    for (int i = 0; i < 9; ++i) ka[i] = P[463 + i];

    // stage x (zero-extended)
    for (int idx = t; idx < AXX * AXU; idx += 256) {
        int a = vert ? (idx % AXX) : (idx / AXU);
        int u = vert ? (idx / AXX) : (idx % AXU);
        int ga = acr0x + a, gl = al0x + u;
        int gy = vert ? gl : ga, gx = vert ? ga : gl;
        xs[a * AXU + u] =
            (gy >= 0 && gy < N && gx >= 0 && gx < N) ? Xb[gy * N + gx] : 0.f;
    }
    __syncthreads();

    // r = f - corr3x3(x,kA), zero outside image
    for (int idx = t; idx < ARR * ARU; idx += 256) {
        int a = vert ? (idx % ARR) : (idx / ARU);
        int u = vert ? (idx / ARR) : (idx % ARU);
        int ga = acr0r + a, gl = al0r + u;
        int gy = vert ? gl : ga, gx = vert ? ga : gl;
        float v = 0.f;
        if (gy >= 0 && gy < N && gx >= 0 && gx < N) {
            float sc = 0.f;
            #pragma unroll
            for (int da = 0; da < 3; ++da)
                #pragma unroll
                for (int dl = 0; dl < 3; ++dl)
                    sc = fmaf(ka[vert ? (dl * 3 + da) : (da * 3 + dl)],
                              xs[(a + da) * AXU + (u + dl)], sc);
            v = Fb[gy * N + gx] - sc;
        }
        rs[a * ARU + u] = v;
    }
    __syncthreads();

    // tmp[m, a, u]: zero if along position outside image (reference zeroing)
    for (int idx = t; idx < 3 * ATA * ATU; idx += 256) {
        int m   = idx / (ATA * ATU);
        int rem = idx - m * (ATA * ATU);
        int a = rem / ATU, u = rem % ATU;
        int gl = (u0 - 3) + u;
        float sc = 0.f;
        if (gl >= 0 && gl < N) {
            for (int da = 0; da < 7; ++da)
                for (int dl = 0; dl < 7; ++dl)
                    sc = fmaf(sw1[m * 49 + (vert ? (dl * 7 + da) : (da * 7 + dl))],
                              rs[(a + da) * ARU + (u + dl)], sc);
        }
        tmp[idx] = sc;
    }
    __syncthreads();

    // outputs: 3 across x 128 along
    for (int idx = t; idx < 3 * 128; idx += 256) {
        int v = idx / 128, u = idx % 128;
        int gl = u0 + u, ga = V0 + v;
        if (vert && gl >= N - 3) continue;   // partial last vertical segment
        float sc = 0.f;
        for (int m = 0; m < 3; ++m)
            for (int d2a = 0; d2a < 7; ++d2a) {
                int aT = v + d2a - 3 + D;    // tmp across index; OOR => ref zeroes
                if (aT < 0 || aT >= ATA) continue;
                for (int d2l = 0; d2l < 7; ++d2l)
                    sc = fmaf(sw2[m * 49 + (vert ? (d2l * 7 + d2a) : (d2a * 7 + d2l))],
                              tmp[(m * ATA + aT) * ATU + (u + d2l)], sc);
            }
        int gy = vert ? gl : ga, gx = vert ? ga : gl;
        float xv = xs[(ga - acr0x) * AXU + (gl - al0x)];
        Ob[gy * N + gx] = xv + sc;
    }
}

// ---------------------------------------------------------------------------
extern "C" void kernel_launch(void* const* d_in, const int* in_sizes, int n_in,
                              void* d_out, int out_size, void* d_ws, size_t ws_size,
                              hipStream_t stream)
{
    const float* x    = (const float*)d_in[0];
    const float* f    = (const float*)d_in[1];
    const float* kA   = (const float*)d_in[2];
    const float* f1w1 = (const float*)d_in[3];
    const float* f1b1 = (const float*)d_in[4];
    const float* f1w2 = (const float*)d_in[5];
    const float* f1b2 = (const float*)d_in[6];
    const float* f2w1 = (const float*)d_in[7];
    const float* f2b1 = (const float*)d_in[8];
    const float* f2w2 = (const float*)d_in[9];
    const float* f2b2 = (const float*)d_in[10];
    float* out    = (float*)d_out;
    float* params = (float*)d_ws;   // BSZ * PS floats = 61440 B

    prep_kernel<<<BSZ, 256, 0, stream>>>(kA, f1w1, f1b1, f1w2, f1b2,
                                         f2w1, f2b1, f2w2, f2b2, params);
    main_kernel<<<dim3(N / TC, N / TR, BSZ), 256, 0, stream>>>(x, f, params, out);
    border_kernel<<<dim3(32, BSZ), 256, 0, stream>>>(x, f, params, out);
}